// Round 1
// baseline (1300.230 us; speedup 1.0000x reference)
//
#include <hip/hip_runtime.h>

#define N_NODES 200000
#define N_EDGES 1000000
#define N_GRAPHS 4096
#define F_IN 11
#define H 64

// ---------------- degree / normalization ----------------

__global__ void deg_kernel(const int* __restrict__ dst, int* __restrict__ deg) {
    int i = blockIdx.x * blockDim.x + threadIdx.x;
    if (i < N_EDGES) atomicAdd(&deg[dst[i]], 1);
}

// in-place: read int degree (indeg), write float dis = rsqrt(indeg + 1)  (+1 = self loop)
__global__ void dis_kernel(int* __restrict__ deg_io) {
    int i = blockIdx.x * blockDim.x + threadIdx.x;
    if (i < N_NODES) {
        int d = deg_io[i] + 1;
        float v = rsqrtf((float)d);
        ((float*)deg_io)[i] = v;
    }
}

// ---------------- dense transform: Y[N,64] = X[N,K] @ W[K,64] ----------------

template <int K>
__global__ void gemm_kernel(const float* __restrict__ X, const float* __restrict__ W,
                            float* __restrict__ Y) {
    __shared__ float Ws[K][H];
    int tid = threadIdx.x;
    for (int i = tid; i < K * H; i += blockDim.x) Ws[i / H][i % H] = W[i];
    __syncthreads();
    int col = tid & 63;
    int r = tid >> 6;                  // 4 rows per 256-thread block
    long row = (long)blockIdx.x * 4 + r;
    if (row >= N_NODES) return;
    const float* xr = X + row * K;
    float acc = 0.f;
#pragma unroll
    for (int k = 0; k < K; ++k) acc += xr[k] * Ws[k][col];
    Y[row * H + col] = acc;
}

// ---------------- edge scatter: A[dst] += B[src] * dis[src]*dis[dst] ----------------

__global__ void scatter_kernel(const int* __restrict__ src, const int* __restrict__ dst,
                               const float* __restrict__ dis,
                               const float* __restrict__ B, float* __restrict__ A) {
    int lane = threadIdx.x & 63;
    int wave = (blockIdx.x * blockDim.x + threadIdx.x) >> 6;
    int nwaves = (gridDim.x * blockDim.x) >> 6;
    for (int e = wave; e < N_EDGES; e += nwaves) {
        int s = src[e];
        int d = dst[e];
        float nrm = dis[s] * dis[d];
        float v = B[(long)s * H + lane] * nrm;
        atomicAdd(&A[(long)d * H + lane], v);
    }
}

// ---------------- finalize: A = act(A + B*dis^2 + bias) ----------------

template <bool RELU>
__global__ void finalize_kernel(float* __restrict__ A, const float* __restrict__ B,
                                const float* __restrict__ dis, const float* __restrict__ bias) {
    long i = (long)blockIdx.x * blockDim.x + threadIdx.x;
    if (i >= (long)N_NODES * H) return;
    int col = (int)(i & 63);
    long row = i >> 6;
    float sn = dis[row];
    sn = sn * sn;                       // self-loop norm = 1/deg
    float v = A[i] + B[i] * sn + bias[col];
    A[i] = RELU ? fmaxf(v, 0.f) : v;
}

// ---------------- mean pool ----------------

__global__ void pool_kernel(const float* __restrict__ A, const int* __restrict__ batch,
                            float* __restrict__ sums, int* __restrict__ cnts) {
    int lane = threadIdx.x & 63;
    int wave = (blockIdx.x * blockDim.x + threadIdx.x) >> 6;
    int nwaves = (gridDim.x * blockDim.x) >> 6;
    for (int n = wave; n < N_NODES; n += nwaves) {
        int g = batch[n];
        atomicAdd(&sums[g * H + lane], A[(long)n * H + lane]);
        if (lane == 0) atomicAdd(&cnts[g], 1);
    }
}

// ---------------- head: out[g] = dot(sums[g], lin_w)/max(cnt,1) + lin_b ----------------

__global__ void head_kernel(const float* __restrict__ sums, const int* __restrict__ cnts,
                            const float* __restrict__ lw, const float* __restrict__ lb,
                            float* __restrict__ out) {
    int lane = threadIdx.x & 63;
    int g = (blockIdx.x * blockDim.x + threadIdx.x) >> 6;
    if (g >= N_GRAPHS) return;
    float v = sums[g * H + lane] * lw[lane];
#pragma unroll
    for (int o = 32; o; o >>= 1) v += __shfl_down(v, o, 64);
    if (lane == 0) {
        float c = (float)cnts[g];
        out[g] = v / fmaxf(c, 1.f) + lb[0];
    }
}

extern "C" void kernel_launch(void* const* d_in, const int* in_sizes, int n_in,
                              void* d_out, int out_size, void* d_ws, size_t ws_size,
                              hipStream_t stream) {
    const float* x     = (const float*)d_in[0];
    const int*   ei    = (const int*)d_in[1];
    const int*   batch = (const int*)d_in[2];
    const float* W1    = (const float*)d_in[3];
    const float* b1    = (const float*)d_in[4];
    const float* W2    = (const float*)d_in[5];
    const float* b2    = (const float*)d_in[6];
    const float* W3    = (const float*)d_in[7];
    const float* b3    = (const float*)d_in[8];
    const float* lw    = (const float*)d_in[9];
    const float* lb    = (const float*)d_in[10];
    float* out = (float*)d_out;

    const int* src = ei;
    const int* dst = ei + N_EDGES;

    const size_t NH = (size_t)N_NODES * H;
    char* ws = (char*)d_ws;
    float* A    = (float*)ws;                                   // 51.2 MB
    float* B    = (float*)(ws + NH * 4);                        // 51.2 MB
    int*   deg  = (int*)(ws + 2 * NH * 4);                      // 0.8 MB (reused as dis f32)
    float* dis  = (float*)deg;
    float* sums = (float*)(ws + 2 * NH * 4 + (size_t)N_NODES * 4);  // 1 MB
    int*   cnts = (int*)((char*)sums + (size_t)N_GRAPHS * H * 4);   // 16 KB

    const int BT = 256;

    // normalization
    hipMemsetAsync(deg, 0, (size_t)N_NODES * 4, stream);
    deg_kernel<<<(N_EDGES + BT - 1) / BT, BT, 0, stream>>>(dst, deg);
    dis_kernel<<<(N_NODES + BT - 1) / BT, BT, 0, stream>>>(deg);

    const int gemm_grid = (N_NODES + 3) / 4;
    const int flat_grid = (int)((NH + BT - 1) / BT);
    const int scat_grid = 4096;

    // layer 1: B = x @ W1 ; A = scatter(B) ; A = relu(A + B*sn + b1)
    gemm_kernel<F_IN><<<gemm_grid, BT, 0, stream>>>(x, W1, B);
    hipMemsetAsync(A, 0, NH * 4, stream);
    scatter_kernel<<<scat_grid, BT, 0, stream>>>(src, dst, dis, B, A);
    finalize_kernel<true><<<flat_grid, BT, 0, stream>>>(A, B, dis, b1);

    // layer 2
    gemm_kernel<H><<<gemm_grid, BT, 0, stream>>>(A, W2, B);
    hipMemsetAsync(A, 0, NH * 4, stream);
    scatter_kernel<<<scat_grid, BT, 0, stream>>>(src, dst, dis, B, A);
    finalize_kernel<true><<<flat_grid, BT, 0, stream>>>(A, B, dis, b2);

    // layer 3 (no relu)
    gemm_kernel<H><<<gemm_grid, BT, 0, stream>>>(A, W3, B);
    hipMemsetAsync(A, 0, NH * 4, stream);
    scatter_kernel<<<scat_grid, BT, 0, stream>>>(src, dst, dis, B, A);
    finalize_kernel<false><<<flat_grid, BT, 0, stream>>>(A, B, dis, b3);

    // pool + head
    hipMemsetAsync(sums, 0, (size_t)N_GRAPHS * H * 4 + (size_t)N_GRAPHS * 4, stream);
    pool_kernel<<<2048, BT, 0, stream>>>(A, batch, sums, cnts);
    head_kernel<<<(N_GRAPHS * 64 + BT - 1) / BT, BT, 0, stream>>>(sums, cnts, lw, lb, out);
}

// Round 4
// 922.650 us; speedup vs baseline: 1.4092x; 1.4092x over previous
//
#include <hip/hip_runtime.h>

#define N_NODES 200000
#define N_EDGES 1000000
#define N_GRAPHS 4096
#define F_IN 11
#define H 64

// ---------------- degree histogram over dst ----------------

__global__ void deg_kernel(const int* __restrict__ dst, int* __restrict__ deg) {
    int i = blockIdx.x * blockDim.x + threadIdx.x;
    if (i < N_EDGES) atomicAdd(&deg[dst[i]], 1);
}

// ---------------- CSR build: block scan + top scan + add + place ----------------

// per-256-block exclusive scan of deg; also emits dis = rsqrt(deg+1)
__global__ void scan_block_kernel(const int* __restrict__ deg, int* __restrict__ ex,
                                  int* __restrict__ bsum, float* __restrict__ dis) {
    __shared__ int sh[256];
    int i = blockIdx.x * 256 + threadIdx.x;
    int v = (i < N_NODES) ? deg[i] : 0;
    if (i < N_NODES) dis[i] = rsqrtf((float)(v + 1));   // +1 self loop
    sh[threadIdx.x] = v;
    __syncthreads();
    for (int o = 1; o < 256; o <<= 1) {
        int t = (threadIdx.x >= o) ? sh[threadIdx.x - o] : 0;
        __syncthreads();
        sh[threadIdx.x] += t;
        __syncthreads();
    }
    if (i < N_NODES) ex[i] = sh[threadIdx.x] - v;       // exclusive
    if (threadIdx.x == 255) bsum[blockIdx.x] = sh[255];
}

// single block: in-place exclusive scan of nb block sums (nb <= 1024)
__global__ void scan_top_kernel(int* __restrict__ bsum, int nb) {
    __shared__ int sh[1024];
    int v = ((int)threadIdx.x < nb) ? bsum[threadIdx.x] : 0;
    sh[threadIdx.x] = v;
    __syncthreads();
    for (int o = 1; o < 1024; o <<= 1) {
        int t = ((int)threadIdx.x >= o) ? sh[threadIdx.x - o] : 0;
        __syncthreads();
        sh[threadIdx.x] += t;
        __syncthreads();
    }
    if ((int)threadIdx.x < nb) bsum[threadIdx.x] = sh[threadIdx.x] - v;
}

__global__ void scan_add_kernel(const int* __restrict__ ex, const int* __restrict__ boff,
                                int* __restrict__ row_start, int* __restrict__ cursor) {
    int i = blockIdx.x * 256 + threadIdx.x;
    if (i >= N_NODES) return;
    int r = ex[i] + boff[i >> 8];
    row_start[i] = r;
    cursor[i] = r;
    if (i == 0) row_start[N_NODES] = N_EDGES;
}

__global__ void place_kernel(const int* __restrict__ src, const int* __restrict__ dst,
                             int* __restrict__ cursor, int* __restrict__ csr) {
    int e = blockIdx.x * blockDim.x + threadIdx.x;
    if (e < N_EDGES) {
        int p = atomicAdd(&cursor[dst[e]], 1);
        csr[p] = src[e];
    }
}

// ---------------- dense transform with dis-scaled epilogue ----------------
// Y[row] = (X[row] @ W) * dis[row]

template <int K>
__global__ void gemm_dis_kernel(const float* __restrict__ X, const float* __restrict__ W,
                                const float* __restrict__ dis, float* __restrict__ Y) {
    __shared__ float Ws[K][H];
    int tid = threadIdx.x;
    for (int i = tid; i < K * H; i += blockDim.x) Ws[i / H][i % H] = W[i];
    __syncthreads();
    int col = tid & 63;
    int r = tid >> 6;                  // 4 rows per 256-thread block
    long row = (long)blockIdx.x * 4 + r;
    if (row >= N_NODES) return;
    const float* xr = X + row * K;
    float acc = 0.f;
#pragma unroll
    for (int k = 0; k < K; ++k) acc += xr[k] * Ws[k][col];
    Y[row * H + col] = acc * dis[row];
}

// ---------------- CSR gather aggregation (atomic-free) ----------------
// A[n] = act( dis[n] * (sum_{s in in(n)} Bs[s] + Bs[n]) + bias )

template <bool RELU>
__global__ void gather_kernel(const int* __restrict__ row_start, const int* __restrict__ csr,
                              const float* __restrict__ Bs, const float* __restrict__ dis,
                              const float* __restrict__ bias, float* __restrict__ A) {
    int lane = threadIdx.x & 63;
    int wave = (blockIdx.x * blockDim.x + threadIdx.x) >> 6;
    int nw = (gridDim.x * blockDim.x) >> 6;
    float bi = bias[lane];
    for (int n = wave; n < N_NODES; n += nw) {
        int e0 = row_start[n], e1 = row_start[n + 1];
        float v = Bs[(long)n * H + lane];            // self loop (Bs already * dis[n])
        for (int e = e0; e < e1; ++e) {
            int s = csr[e];
            v += Bs[(long)s * H + lane];
        }
        v = v * dis[n] + bi;
        A[(long)n * H + lane] = RELU ? fmaxf(v, 0.f) : v;
    }
}

// layer-3 gather with fused mean-pool accumulation
__global__ void gather_pool_kernel(const int* __restrict__ row_start, const int* __restrict__ csr,
                                   const float* __restrict__ Bs, const float* __restrict__ dis,
                                   const float* __restrict__ bias, const int* __restrict__ batch,
                                   float* __restrict__ sums, int* __restrict__ cnts) {
    int lane = threadIdx.x & 63;
    int wave = (blockIdx.x * blockDim.x + threadIdx.x) >> 6;
    int nw = (gridDim.x * blockDim.x) >> 6;
    float bi = bias[lane];
    for (int n = wave; n < N_NODES; n += nw) {
        int e0 = row_start[n], e1 = row_start[n + 1];
        float v = Bs[(long)n * H + lane];
        for (int e = e0; e < e1; ++e) {
            int s = csr[e];
            v += Bs[(long)s * H + lane];
        }
        v = v * dis[n] + bi;
        int g = batch[n];
        atomicAdd(&sums[g * H + lane], v);
        if (lane == 0) atomicAdd(&cnts[g], 1);
    }
}

// ---------------- head: out[g] = dot(sums[g], lin_w)/max(cnt,1) + lin_b ----------------

__global__ void head_kernel(const float* __restrict__ sums, const int* __restrict__ cnts,
                            const float* __restrict__ lw, const float* __restrict__ lb,
                            float* __restrict__ out) {
    int lane = threadIdx.x & 63;
    int g = (blockIdx.x * blockDim.x + threadIdx.x) >> 6;
    if (g >= N_GRAPHS) return;
    float v = sums[g * H + lane] * lw[lane];
#pragma unroll
    for (int o = 32; o; o >>= 1) v += __shfl_down(v, o, 64);
    if (lane == 0) {
        float c = (float)cnts[g];
        out[g] = v / fmaxf(c, 1.f) + lb[0];
    }
}

extern "C" void kernel_launch(void* const* d_in, const int* in_sizes, int n_in,
                              void* d_out, int out_size, void* d_ws, size_t ws_size,
                              hipStream_t stream) {
    const float* x     = (const float*)d_in[0];
    const int*   ei    = (const int*)d_in[1];
    const int*   batch = (const int*)d_in[2];
    const float* W1    = (const float*)d_in[3];
    const float* b1    = (const float*)d_in[4];
    const float* W2    = (const float*)d_in[5];
    const float* b2    = (const float*)d_in[6];
    const float* W3    = (const float*)d_in[7];
    const float* b3    = (const float*)d_in[8];
    const float* lw    = (const float*)d_in[9];
    const float* lb    = (const float*)d_in[10];
    float* out = (float*)d_out;

    const int* src = ei;
    const int* dst = ei + N_EDGES;

    const size_t NH = (size_t)N_NODES * H;
    char* ws = (char*)d_ws;
    // persistent buffers
    float* A         = (float*)ws;                                    // 51.2 MB
    float* Bs        = (float*)(ws + NH * 4);                         // 51.2 MB
    float* dis       = (float*)(ws + 2 * NH * 4);                     // 0.8 MB
    int*   row_start = (int*)(ws + 2 * NH * 4 + (size_t)N_NODES * 4); // 0.8 MB (+1 sentinel)
    int*   csr       = (int*)((char*)row_start + ((size_t)N_NODES + 1) * 4); // 4 MB
    float* sums      = (float*)((char*)csr + (size_t)N_EDGES * 4);    // 1 MB
    int*   cnts      = (int*)((char*)sums + (size_t)N_GRAPHS * H * 4); // 16 KB
    // transients aliased into A (A first written after CSR build completes)
    int*   deg    = (int*)A;
    int*   ex     = (int*)((char*)A + (size_t)N_NODES * 4);
    int*   cursor = (int*)((char*)A + 2 * (size_t)N_NODES * 4);
    int*   bsum   = (int*)((char*)A + 3 * (size_t)N_NODES * 4);

    const int BT = 256;
    const int NB_NODES = (N_NODES + 255) / 256;          // 782
    const int gemm_grid = (N_NODES + 3) / 4;
    const int gath_grid = 2048;

    // ---- CSR build + normalization ----
    hipMemsetAsync(deg, 0, (size_t)N_NODES * 4, stream);
    deg_kernel<<<(N_EDGES + BT - 1) / BT, BT, 0, stream>>>(dst, deg);
    scan_block_kernel<<<NB_NODES, 256, 0, stream>>>(deg, ex, bsum, dis);
    scan_top_kernel<<<1, 1024, 0, stream>>>(bsum, NB_NODES);
    scan_add_kernel<<<NB_NODES, 256, 0, stream>>>(ex, bsum, row_start, cursor);
    place_kernel<<<(N_EDGES + BT - 1) / BT, BT, 0, stream>>>(src, dst, cursor, csr);

    // ---- layer 1 ----
    gemm_dis_kernel<F_IN><<<gemm_grid, BT, 0, stream>>>(x, W1, dis, Bs);
    gather_kernel<true><<<gath_grid, BT, 0, stream>>>(row_start, csr, Bs, dis, b1, A);

    // ---- layer 2 ----
    gemm_dis_kernel<H><<<gemm_grid, BT, 0, stream>>>(A, W2, dis, Bs);
    gather_kernel<true><<<gath_grid, BT, 0, stream>>>(row_start, csr, Bs, dis, b2, A);

    // ---- layer 3 + fused mean pool ----
    gemm_dis_kernel<H><<<gemm_grid, BT, 0, stream>>>(A, W3, dis, Bs);
    hipMemsetAsync(sums, 0, (size_t)N_GRAPHS * H * 4 + (size_t)N_GRAPHS * 4, stream);
    gather_pool_kernel<<<gath_grid, BT, 0, stream>>>(row_start, csr, Bs, dis, b3, batch,
                                                     sums, cnts);

    // ---- head ----
    head_kernel<<<(N_GRAPHS * 64 + BT - 1) / BT, BT, 0, stream>>>(sums, cnts, lw, lb, out);
}

// Round 5
// 636.896 us; speedup vs baseline: 2.0415x; 1.4487x over previous
//
#include <hip/hip_runtime.h>

#define N_NODES 200000
#define N_EDGES 1000000
#define N_GRAPHS 4096
#define F_IN 11
#define H 64

// ---------------- degree histogram over dst ----------------

__global__ void deg_kernel(const int* __restrict__ dst, int* __restrict__ deg) {
    int i = blockIdx.x * blockDim.x + threadIdx.x;
    if (i < N_EDGES) atomicAdd(&deg[dst[i]], 1);
}

// ---------------- CSR build: block scan + top scan + add + place ----------------

__global__ void scan_block_kernel(const int* __restrict__ deg, int* __restrict__ ex,
                                  int* __restrict__ bsum, float* __restrict__ dis) {
    __shared__ int sh[256];
    int i = blockIdx.x * 256 + threadIdx.x;
    int v = (i < N_NODES) ? deg[i] : 0;
    if (i < N_NODES) dis[i] = rsqrtf((float)(v + 1));   // +1 self loop
    sh[threadIdx.x] = v;
    __syncthreads();
    for (int o = 1; o < 256; o <<= 1) {
        int t = (threadIdx.x >= o) ? sh[threadIdx.x - o] : 0;
        __syncthreads();
        sh[threadIdx.x] += t;
        __syncthreads();
    }
    if (i < N_NODES) ex[i] = sh[threadIdx.x] - v;       // exclusive
    if (threadIdx.x == 255) bsum[blockIdx.x] = sh[255];
}

__global__ void scan_top_kernel(int* __restrict__ bsum, int nb) {
    __shared__ int sh[1024];
    int v = ((int)threadIdx.x < nb) ? bsum[threadIdx.x] : 0;
    sh[threadIdx.x] = v;
    __syncthreads();
    for (int o = 1; o < 1024; o <<= 1) {
        int t = ((int)threadIdx.x >= o) ? sh[threadIdx.x - o] : 0;
        __syncthreads();
        sh[threadIdx.x] += t;
        __syncthreads();
    }
    if ((int)threadIdx.x < nb) bsum[threadIdx.x] = sh[threadIdx.x] - v;
}

__global__ void scan_add_kernel(const int* __restrict__ ex, const int* __restrict__ boff,
                                int* __restrict__ row_start, int* __restrict__ cursor) {
    int i = blockIdx.x * 256 + threadIdx.x;
    if (i >= N_NODES) return;
    int r = ex[i] + boff[i >> 8];
    row_start[i] = r;
    cursor[i] = r;
    if (i == 0) row_start[N_NODES] = N_EDGES;
}

__global__ void place_kernel(const int* __restrict__ src, const int* __restrict__ dst,
                             int* __restrict__ cursor, int* __restrict__ csr) {
    int e = blockIdx.x * blockDim.x + threadIdx.x;
    if (e < N_EDGES) {
        int p = atomicAdd(&cursor[dst[e]], 1);
        csr[p] = src[e];
    }
}

// ---------------- register-tiled dense transform ----------------
// Y[row] = (X[row] @ W) * dis[row]; 64 rows/block, 256 threads, 4x4 per thread.
// Xt is the X tile TRANSPOSED in LDS (stride 68 floats = 272 B, 16B-aligned)
// so the inner loop is 2x ds_read_b128 + 16 FMA per k.

template <int K>
__global__ void gemm_tile_kernel(const float* __restrict__ X, const float* __restrict__ W,
                                 const float* __restrict__ dis, float* __restrict__ Y) {
    __shared__ float Xt[K][68];
    __shared__ float Ws[K][64];
    int tid = threadIdx.x;
    int rowbase = blockIdx.x * 64;

    for (int i = tid; i < K * 64; i += 256) Ws[i >> 6][i & 63] = W[i];

    if (K == 64) {
        // 64x64 tile = 1024 float4, 4 per thread, transpose on LDS write
        for (int t = tid; t < 1024; t += 256) {
            int r = t >> 4;
            int kc = (t & 15) * 4;
            float4 v = *(const float4*)(X + (size_t)(rowbase + r) * 64 + kc);
            Xt[kc + 0][r] = v.x;
            Xt[kc + 1][r] = v.y;
            Xt[kc + 2][r] = v.z;
            Xt[kc + 3][r] = v.w;
        }
    } else {
        // K==11: 64*11 = 704 consecutive floats = 176 float4
        const float* base = X + (size_t)rowbase * K;
        for (int t = tid; t < (64 * K) / 4; t += 256) {
            float4 v = *(const float4*)(base + t * 4);
            float vv[4] = {v.x, v.y, v.z, v.w};
#pragma unroll
            for (int j = 0; j < 4; ++j) {
                int flat = t * 4 + j;
                int r = flat / K;
                int k = flat - r * K;
                Xt[k][r] = vv[j];
            }
        }
    }
    __syncthreads();

    int tc = (tid & 15) * 4;
    int tr = (tid >> 4) * 4;
    float a00 = 0, a01 = 0, a02 = 0, a03 = 0;
    float a10 = 0, a11 = 0, a12 = 0, a13 = 0;
    float a20 = 0, a21 = 0, a22 = 0, a23 = 0;
    float a30 = 0, a31 = 0, a32 = 0, a33 = 0;
#pragma unroll
    for (int k = 0; k < K; ++k) {
        float4 xv = *(const float4*)&Xt[k][tr];
        float4 wv = *(const float4*)&Ws[k][tc];
        a00 += xv.x * wv.x; a01 += xv.x * wv.y; a02 += xv.x * wv.z; a03 += xv.x * wv.w;
        a10 += xv.y * wv.x; a11 += xv.y * wv.y; a12 += xv.y * wv.z; a13 += xv.y * wv.w;
        a20 += xv.z * wv.x; a21 += xv.z * wv.y; a22 += xv.z * wv.z; a23 += xv.z * wv.w;
        a30 += xv.w * wv.x; a31 += xv.w * wv.y; a32 += xv.w * wv.z; a33 += xv.w * wv.w;
    }
    float acc[4][4] = {{a00, a01, a02, a03}, {a10, a11, a12, a13},
                       {a20, a21, a22, a23}, {a30, a31, a32, a33}};
#pragma unroll
    for (int i = 0; i < 4; ++i) {
        int row = rowbase + tr + i;
        float d = dis[row];
        float4 o;
        o.x = acc[i][0] * d; o.y = acc[i][1] * d; o.z = acc[i][2] * d; o.w = acc[i][3] * d;
        *(float4*)(Y + (size_t)row * 64 + tc) = o;
    }
}

// ---------------- CSR gather aggregation (atomic-free) ----------------
// A[n] = act( dis[n] * (sum_{s in in(n)} Bs[s] + Bs[n]) + bias )

template <bool RELU>
__global__ void gather_kernel(const int* __restrict__ row_start, const int* __restrict__ csr,
                              const float* __restrict__ Bs, const float* __restrict__ dis,
                              const float* __restrict__ bias, float* __restrict__ A) {
    int lane = threadIdx.x & 63;
    int wave = (blockIdx.x * blockDim.x + threadIdx.x) >> 6;
    int nw = (gridDim.x * blockDim.x) >> 6;
    float bi = bias[lane];
    for (int n = wave; n < N_NODES; n += nw) {
        int e0 = row_start[n], e1 = row_start[n + 1];
        float v = Bs[(long)n * H + lane];            // self loop (Bs already * dis[n])
        for (int e = e0; e < e1; ++e) {
            int s = csr[e];
            v += Bs[(long)s * H + lane];
        }
        v = v * dis[n] + bi;
        A[(long)n * H + lane] = RELU ? fmaxf(v, 0.f) : v;
    }
}

// layer-3 gather with fused mean-pool accumulation
__global__ void gather_pool_kernel(const int* __restrict__ row_start, const int* __restrict__ csr,
                                   const float* __restrict__ Bs, const float* __restrict__ dis,
                                   const float* __restrict__ bias, const int* __restrict__ batch,
                                   float* __restrict__ sums, int* __restrict__ cnts) {
    int lane = threadIdx.x & 63;
    int wave = (blockIdx.x * blockDim.x + threadIdx.x) >> 6;
    int nw = (gridDim.x * blockDim.x) >> 6;
    float bi = bias[lane];
    for (int n = wave; n < N_NODES; n += nw) {
        int e0 = row_start[n], e1 = row_start[n + 1];
        float v = Bs[(long)n * H + lane];
        for (int e = e0; e < e1; ++e) {
            int s = csr[e];
            v += Bs[(long)s * H + lane];
        }
        v = v * dis[n] + bi;
        int g = batch[n];
        atomicAdd(&sums[g * H + lane], v);
        if (lane == 0) atomicAdd(&cnts[g], 1);
    }
}

// ---------------- head ----------------

__global__ void head_kernel(const float* __restrict__ sums, const int* __restrict__ cnts,
                            const float* __restrict__ lw, const float* __restrict__ lb,
                            float* __restrict__ out) {
    int lane = threadIdx.x & 63;
    int g = (blockIdx.x * blockDim.x + threadIdx.x) >> 6;
    if (g >= N_GRAPHS) return;
    float v = sums[g * H + lane] * lw[lane];
#pragma unroll
    for (int o = 32; o; o >>= 1) v += __shfl_down(v, o, 64);
    if (lane == 0) {
        float c = (float)cnts[g];
        out[g] = v / fmaxf(c, 1.f) + lb[0];
    }
}

extern "C" void kernel_launch(void* const* d_in, const int* in_sizes, int n_in,
                              void* d_out, int out_size, void* d_ws, size_t ws_size,
                              hipStream_t stream) {
    const float* x     = (const float*)d_in[0];
    const int*   ei    = (const int*)d_in[1];
    const int*   batch = (const int*)d_in[2];
    const float* W1    = (const float*)d_in[3];
    const float* b1    = (const float*)d_in[4];
    const float* W2    = (const float*)d_in[5];
    const float* b2    = (const float*)d_in[6];
    const float* W3    = (const float*)d_in[7];
    const float* b3    = (const float*)d_in[8];
    const float* lw    = (const float*)d_in[9];
    const float* lb    = (const float*)d_in[10];
    float* out = (float*)d_out;

    const int* src = ei;
    const int* dst = ei + N_EDGES;

    const size_t NH = (size_t)N_NODES * H;
    char* ws = (char*)d_ws;
    float* A         = (float*)ws;                                    // 51.2 MB
    float* Bs        = (float*)(ws + NH * 4);                         // 51.2 MB
    float* dis       = (float*)(ws + 2 * NH * 4);                     // 0.8 MB
    int*   row_start = (int*)(ws + 2 * NH * 4 + (size_t)N_NODES * 4); // 0.8 MB (+1)
    int*   csr       = (int*)((char*)row_start + ((size_t)N_NODES + 1) * 4); // 4 MB
    float* sums      = (float*)((char*)csr + (size_t)N_EDGES * 4);    // 1 MB
    int*   cnts      = (int*)((char*)sums + (size_t)N_GRAPHS * H * 4); // 16 KB
    // transients aliased into A (A first written after CSR build completes)
    int*   deg    = (int*)A;
    int*   ex     = (int*)((char*)A + (size_t)N_NODES * 4);
    int*   cursor = (int*)((char*)A + 2 * (size_t)N_NODES * 4);
    int*   bsum   = (int*)((char*)A + 3 * (size_t)N_NODES * 4);

    const int BT = 256;
    const int NB_NODES = (N_NODES + 255) / 256;          // 782
    const int gemm_grid = N_NODES / 64;                  // 3125 (exact)
    const int gath_grid = 2048;

    // ---- CSR build + normalization ----
    hipMemsetAsync(deg, 0, (size_t)N_NODES * 4, stream);
    deg_kernel<<<(N_EDGES + BT - 1) / BT, BT, 0, stream>>>(dst, deg);
    scan_block_kernel<<<NB_NODES, 256, 0, stream>>>(deg, ex, bsum, dis);
    scan_top_kernel<<<1, 1024, 0, stream>>>(bsum, NB_NODES);
    scan_add_kernel<<<NB_NODES, 256, 0, stream>>>(ex, bsum, row_start, cursor);
    place_kernel<<<(N_EDGES + BT - 1) / BT, BT, 0, stream>>>(src, dst, cursor, csr);

    // ---- layer 1 ----
    gemm_tile_kernel<F_IN><<<gemm_grid, BT, 0, stream>>>(x, W1, dis, Bs);
    gather_kernel<true><<<gath_grid, BT, 0, stream>>>(row_start, csr, Bs, dis, b1, A);

    // ---- layer 2 ----
    gemm_tile_kernel<H><<<gemm_grid, BT, 0, stream>>>(A, W2, dis, Bs);
    gather_kernel<true><<<gath_grid, BT, 0, stream>>>(row_start, csr, Bs, dis, b2, A);

    // ---- layer 3 + fused mean pool ----
    gemm_tile_kernel<H><<<gemm_grid, BT, 0, stream>>>(A, W3, dis, Bs);
    hipMemsetAsync(sums, 0, (size_t)N_GRAPHS * H * 4 + (size_t)N_GRAPHS * 4, stream);
    gather_pool_kernel<<<gath_grid, BT, 0, stream>>>(row_start, csr, Bs, dis, b3, batch,
                                                     sums, cnts);

    // ---- head ----
    head_kernel<<<(N_GRAPHS * 64 + BT - 1) / BT, BT, 0, stream>>>(sums, cnts, lw, lb, out);
}